// Round 1
// baseline (30154.993 us; speedup 1.0000x reference)
//
#include <hip/hip_runtime.h>

#define SEQ   512
#define BATCH 64
#define DIN   512
#define DH    512
#define KTOT  1024   // DIN + DH
#define NWG   256
#define NTH   256

__device__ __forceinline__ float sig_(float v) { return 1.0f / (1.0f + __expf(-v)); }

// Persistent LSTM kernel.
// Grid: 256 WGs (1 per CU, co-resident). Block: 256 threads = 4 waves.
//   wave (tid>>6) = gate index: 0=f, 1=i, 2=g, 3=o
//   lane (tid&63) = batch index b
//   WG wg owns output columns j0 = 2*wg and j0+1.
// Each wave computes preact(gate, j0, b) and preact(gate, j0+1, b) as full
// K=1024 fp32 dot products in registers (weights are wave-uniform -> SMEM).
// h_t is written into the stacked output and re-read as h_{t-1}; c stays in
// thread registers (threads 0..127). One device-wide epoch barrier per step.
__global__ __launch_bounds__(NTH, 1)
void lstm_persistent(const float* __restrict__ x,
                     const float* __restrict__ Wf, const float* __restrict__ bf,
                     const float* __restrict__ Wi, const float* __restrict__ bi,
                     const float* __restrict__ Wgg, const float* __restrict__ bg,
                     const float* __restrict__ Wo, const float* __restrict__ bo,
                     float* __restrict__ out,
                     unsigned int* __restrict__ barcnt)
{
    const int tid  = threadIdx.x;
    const int lane = tid & 63;                                   // batch b
    const int gate = __builtin_amdgcn_readfirstlane(tid >> 6);   // wave -> gate
    const int wg   = blockIdx.x;
    const int j0   = wg * 2;

    const float* const Warr[4] = {Wf, Wi, Wgg, Wo};
    const float* const barr[4] = {bf, bi, bg, bo};
    const float* const w0 = Warr[gate] + (size_t)j0 * KTOT;   // row j0, len 1024
    const float* const w1 = w0 + KTOT;                        // row j0+1
    const float bias0 = barr[gate][j0];
    const float bias1 = barr[gate][j0 + 1];

    __shared__ float pre[4][2][64];   // [gate][jloc][b]

    float c_state = 0.0f;             // owned by threads 0..127: (b=tid&63, jl=tid>>6)

    float* const hx_out = out + (size_t)SEQ * BATCH * DH;
    float* const cx_out = hx_out + (size_t)BATCH * DH;

    for (int t = 0; t < SEQ; ++t) {
        // -------- preactivation dot products (fp32, 4 chains per output) ----
        float4 A0 = make_float4(0.f, 0.f, 0.f, 0.f);
        float4 A1 = make_float4(0.f, 0.f, 0.f, 0.f);

        {   // x half: k in [0, 512)
            const float* cr = x + ((size_t)t * BATCH + lane) * DIN;
            #pragma unroll 8
            for (int k = 0; k < DIN; k += 4) {
                const float4 c4 = *(const float4*)(cr + k);
                A0.x = fmaf(c4.x, w0[k + 0], A0.x);
                A0.y = fmaf(c4.y, w0[k + 1], A0.y);
                A0.z = fmaf(c4.z, w0[k + 2], A0.z);
                A0.w = fmaf(c4.w, w0[k + 3], A0.w);
                A1.x = fmaf(c4.x, w1[k + 0], A1.x);
                A1.y = fmaf(c4.y, w1[k + 1], A1.y);
                A1.z = fmaf(c4.z, w1[k + 2], A1.z);
                A1.w = fmaf(c4.w, w1[k + 3], A1.w);
            }
        }
        if (t > 0) {   // h half: k in [512, 1024); h_0 == 0 so skip at t==0
            const float* hr  = out + ((size_t)(t - 1) * BATCH + lane) * DH;
            const float* w0h = w0 + DIN;
            const float* w1h = w1 + DIN;
            #pragma unroll 8
            for (int k = 0; k < DH; k += 4) {
                const float4 c4 = *(const float4*)(hr + k);
                A0.x = fmaf(c4.x, w0h[k + 0], A0.x);
                A0.y = fmaf(c4.y, w0h[k + 1], A0.y);
                A0.z = fmaf(c4.z, w0h[k + 2], A0.z);
                A0.w = fmaf(c4.w, w0h[k + 3], A0.w);
                A1.x = fmaf(c4.x, w1h[k + 0], A1.x);
                A1.y = fmaf(c4.y, w1h[k + 1], A1.y);
                A1.z = fmaf(c4.z, w1h[k + 2], A1.z);
                A1.w = fmaf(c4.w, w1h[k + 3], A1.w);
            }
        }

        pre[gate][0][lane] = (A0.x + A0.y) + (A0.z + A0.w) + bias0;
        pre[gate][1][lane] = (A1.x + A1.y) + (A1.z + A1.w) + bias1;
        __syncthreads();

        // -------- gate math + state update (threads 0..127) -----------------
        if (tid < 128) {
            const int b  = tid & 63;
            const int jl = tid >> 6;
            const float fg = sig_(pre[0][jl][b]);
            const float ig = sig_(pre[1][jl][b]);
            const float gg = tanhf(pre[2][jl][b]);
            const float og = sig_(pre[3][jl][b]);
            c_state = fmaf(fg, c_state, ig * gg);
            const float h = og * tanhf(c_state);
            out[((size_t)t * BATCH + b) * DH + (size_t)(j0 + jl)] = h;
            if (t == SEQ - 1) {
                hx_out[(size_t)b * DH + (size_t)(j0 + jl)] = h;
                cx_out[(size_t)b * DH + (size_t)(j0 + jl)] = c_state;
            }
        }
        __syncthreads();   // pre[] reusable; h stores drained (vmcnt(0) before s_barrier)

        // -------- device-wide epoch barrier (skip after last step) ----------
        if (t < SEQ - 1) {
            if (tid == 0) {
                __hip_atomic_fetch_add(barcnt, 1u, __ATOMIC_RELEASE,
                                       __HIP_MEMORY_SCOPE_AGENT);
                const unsigned int target = (unsigned int)NWG * (unsigned int)(t + 1);
                while (__hip_atomic_load(barcnt, __ATOMIC_ACQUIRE,
                                         __HIP_MEMORY_SCOPE_AGENT) < target) {
                    __builtin_amdgcn_s_sleep(4);
                }
            }
            __syncthreads();
        }
    }
}

extern "C" void kernel_launch(void* const* d_in, const int* in_sizes, int n_in,
                              void* d_out, int out_size, void* d_ws, size_t ws_size,
                              hipStream_t stream)
{
    const float* x  = (const float*)d_in[0];
    const float* Wf = (const float*)d_in[1];
    const float* bf = (const float*)d_in[2];
    const float* Wi = (const float*)d_in[3];
    const float* bi = (const float*)d_in[4];
    const float* Wg = (const float*)d_in[5];
    const float* bg = (const float*)d_in[6];
    const float* Wo = (const float*)d_in[7];
    const float* bo = (const float*)d_in[8];
    float* out = (float*)d_out;

    unsigned int* barcnt = (unsigned int*)d_ws;
    // Barrier counter must start at 0 every call (ws is poisoned 0xAA once and
    // never re-poisoned between replays). hipMemsetAsync is graph-capturable.
    hipMemsetAsync(d_ws, 0, 256, stream);

    lstm_persistent<<<NWG, NTH, 0, stream>>>(x, Wf, bf, Wi, bi, Wg, bg, Wo, bo,
                                             out, barcnt);
}

// Round 2
// 10237.873 us; speedup vs baseline: 2.9454x; 2.9454x over previous
//
#include <hip/hip_runtime.h>

#define SEQ   512
#define BATCH 64
#define DIN   512
#define DH    512
#define KTOT  1024   // DIN + DH
#define NWG   256
#define NTH   1024   // 16 waves

__device__ __forceinline__ float sig_(float v) { return 1.0f / (1.0f + __expf(-v)); }

// Persistent LSTM, round 2.
// Grid: 256 WGs (1/CU). Block: 1024 threads = 16 waves (4/SIMD -> 50% occ).
// WG owns 2 h-columns j0=2*wg, j0+1 across all 4 gates => 8 weight rows,
// staged in LDS once (32 KB) and re-read (uniform broadcast) all 512 steps.
// Wave w owns K-slice [w*32, w*32+32) of BOTH the x-half and h-half; lane = b.
// Per step: phase A (x-contrib, barrier-independent) -> epoch-barrier wait
// (relaxed spin, hidden behind A) -> phase B (h-contrib) -> LDS partial
// reduce over 16 waves -> gate math (threads 0..127, c in registers) ->
// h store -> release-add.
__global__ __launch_bounds__(NTH, 4)
void lstm_persistent(const float* __restrict__ x,
                     const float* __restrict__ Wff, const float* __restrict__ bff,
                     const float* __restrict__ Wii, const float* __restrict__ bii,
                     const float* __restrict__ Wgg, const float* __restrict__ bgg,
                     const float* __restrict__ Woo, const float* __restrict__ boo,
                     float* __restrict__ out,
                     unsigned int* __restrict__ barcnt)
{
    extern __shared__ float smem[];
    float* const wlds = smem;          // [8][1024] weight rows, r = gate*2 + jl
    float* const part = smem + 8192;   // [16][8][64] wave partials (pre aliased at w=0)

    const int tid = threadIdx.x;
    const int b   = tid & 63;          // lane = batch
    const int w   = tid >> 6;          // wave = K-slice
    const int j0  = (int)blockIdx.x * 2;

    const float* const Wgate[4] = {Wff, Wii, Wgg, Woo};
    const float* const Bgate[4] = {bff, bii, bgg, boo};

    // ---- stage the WG's 8 weight rows into LDS (once) ----
    {
        const int f0 = tid * 8;                 // 8 floats per thread, 8192 total
        const int r  = f0 >> 10;
        const int k  = f0 & 1023;
        const float* src = Wgate[r >> 1] + (size_t)(j0 + (r & 1)) * KTOT + k;
        const float4 v0 = ((const float4*)src)[0];
        const float4 v1 = ((const float4*)src)[1];
        ((float4*)(wlds + f0))[0] = v0;
        ((float4*)(wlds + f0))[1] = v1;
    }
    float bias_r = 0.0f;
    if (tid < 512) {
        const int r = tid >> 6;
        bias_r = Bgate[r >> 1][j0 + (r & 1)];
    }
    __syncthreads();

    const int k0 = w * 32;             // this wave's 32-wide slice of [0,512)
    float c_state = 0.0f;              // live in threads 0..127 (jl = tid>>6)

    float* const hx_out = out + (size_t)SEQ * BATCH * DH;
    float* const cx_out = hx_out + (size_t)BATCH * DH;

    for (int t = 0; t < SEQ; ++t) {
        float acc[8] = {0.f, 0.f, 0.f, 0.f, 0.f, 0.f, 0.f, 0.f};

        // ---------- phase A: x contribution (no dependence on h[t-1]) ------
        {
            const float4* xr = (const float4*)(x + ((size_t)t * BATCH + b) * DIN + k0);
            #pragma unroll
            for (int i = 0; i < 8; ++i) {
                const float4 a4 = xr[i];
                #pragma unroll
                for (int r = 0; r < 8; ++r) {
                    const float4 w4 = *(const float4*)(wlds + r * KTOT + k0 + i * 4);
                    acc[r] = fmaf(a4.x, w4.x, acc[r]);
                    acc[r] = fmaf(a4.y, w4.y, acc[r]);
                    acc[r] = fmaf(a4.z, w4.z, acc[r]);
                    acc[r] = fmaf(a4.w, w4.w, acc[r]);
                }
            }
        }

        if (t > 0) {
            // ------ epoch barrier: relaxed spin, one acquire at exit -------
            if (tid == 0) {
                const unsigned int target = (unsigned int)NWG * (unsigned int)t;
                while (__hip_atomic_load(barcnt, __ATOMIC_RELAXED,
                                         __HIP_MEMORY_SCOPE_AGENT) < target) {
                    __builtin_amdgcn_s_sleep(2);
                }
                (void)__hip_atomic_load(barcnt, __ATOMIC_ACQUIRE,
                                        __HIP_MEMORY_SCOPE_AGENT);
            }
            __syncthreads();   // S1

            // ---------- phase B: h contribution ----------------------------
            const float4* hr = (const float4*)(out + ((size_t)(t - 1) * BATCH + b) * DH + k0);
            #pragma unroll
            for (int i = 0; i < 8; ++i) {
                const float4 a4 = hr[i];
                #pragma unroll
                for (int r = 0; r < 8; ++r) {
                    const float4 w4 = *(const float4*)(wlds + r * KTOT + 512 + k0 + i * 4);
                    acc[r] = fmaf(a4.x, w4.x, acc[r]);
                    acc[r] = fmaf(a4.y, w4.y, acc[r]);
                    acc[r] = fmaf(a4.z, w4.z, acc[r]);
                    acc[r] = fmaf(a4.w, w4.w, acc[r]);
                }
            }
        }

        // ---------- write per-wave partials --------------------------------
        #pragma unroll
        for (int r = 0; r < 8; ++r) part[(w * 8 + r) * 64 + b] = acc[r];
        __syncthreads();   // S2

        // ---------- reduce over the 16 K-slices ----------------------------
        if (tid < 512) {
            const int r = tid >> 6;
            float v = bias_r;
            #pragma unroll
            for (int ww = 0; ww < 16; ++ww) v += part[(ww * 8 + r) * 64 + b];
            part[r * 64 + b] = v;     // pre[r][b], aliased into w=0 slot
        }
        __syncthreads();   // S3

        // ---------- gate math + state update (threads 0..127) --------------
        if (tid < 128) {
            const int jl = tid >> 6;
            const float fg = sig_(part[(0 + jl) * 64 + b]);
            const float ig = sig_(part[(2 + jl) * 64 + b]);
            const float gg = tanhf(part[(4 + jl) * 64 + b]);
            const float og = sig_(part[(6 + jl) * 64 + b]);
            c_state = fmaf(fg, c_state, ig * gg);
            const float h = og * tanhf(c_state);
            out[((size_t)t * BATCH + b) * DH + (size_t)(j0 + jl)] = h;
            if (t == SEQ - 1) {
                hx_out[(size_t)b * DH + (size_t)(j0 + jl)] = h;
                cx_out[(size_t)b * DH + (size_t)(j0 + jl)] = c_state;
            }
        }

        if (t < SEQ - 1) {
            __syncthreads();   // S4: h stores drained (vmcnt 0) before signal
            if (tid == 0) {
                __hip_atomic_fetch_add(barcnt, 1u, __ATOMIC_RELEASE,
                                       __HIP_MEMORY_SCOPE_AGENT);
            }
        }
    }
}

extern "C" void kernel_launch(void* const* d_in, const int* in_sizes, int n_in,
                              void* d_out, int out_size, void* d_ws, size_t ws_size,
                              hipStream_t stream)
{
    const float* x  = (const float*)d_in[0];
    const float* Wf = (const float*)d_in[1];
    const float* bf = (const float*)d_in[2];
    const float* Wi = (const float*)d_in[3];
    const float* bi = (const float*)d_in[4];
    const float* Wg = (const float*)d_in[5];
    const float* bg = (const float*)d_in[6];
    const float* Wo = (const float*)d_in[7];
    const float* bo = (const float*)d_in[8];
    float* out = (float*)d_out;

    unsigned int* barcnt = (unsigned int*)d_ws;
    // Counter must be 0 at every launch (ws poisoned 0xAA once, never restored).
    hipMemsetAsync(d_ws, 0, 256, stream);

    static bool attr_set = false;
    if (!attr_set) {   // idempotent host-side kernel attribute; not a stream op
        hipFuncSetAttribute((const void*)lstm_persistent,
                            hipFuncAttributeMaxDynamicSharedMemorySize, 65536);
        attr_set = true;
    }

    lstm_persistent<<<NWG, NTH, 65536, stream>>>(x, Wf, bf, Wi, bi, Wg, bg,
                                                 Wo, bo, out, barcnt);
}

// Round 3
// 4870.066 us; speedup vs baseline: 6.1919x; 2.1022x over previous
//
#include <hip/hip_runtime.h>

#define SEQ   512
#define BATCH 64
#define DIN   512
#define DH    512
#define KTOT  1024
#define NWG   128
#define NTH   256
#define HBUF_BYTES 65536   // 4 mt * 16 kt * 64 lanes * 16 B

typedef __attribute__((ext_vector_type(8))) short short8;   // 8 x bf16
typedef __attribute__((ext_vector_type(4))) float f32x4;

__device__ __forceinline__ float sig_(float v) { return 1.0f / (1.0f + __expf(-v)); }

// fp32 -> bf16 RNE (finite inputs), dependency-free
__device__ __forceinline__ unsigned short f2bf(float f) {
    unsigned int u = __float_as_uint(f);
    return (unsigned short)((u + 0x7fffu + ((u >> 16) & 1u)) >> 16);
}

__device__ __forceinline__ short8 cvt8(float4 lo, float4 hi) {
    short8 r;
    r[0] = (short)f2bf(lo.x); r[1] = (short)f2bf(lo.y);
    r[2] = (short)f2bf(lo.z); r[3] = (short)f2bf(lo.w);
    r[4] = (short)f2bf(hi.x); r[5] = (short)f2bf(hi.y);
    r[6] = (short)f2bf(hi.z); r[7] = (short)f2bf(hi.w);
    return r;
}

// Persistent MFMA LSTM.
// 128 WGs x 256 threads (4 waves). WG wg owns h-columns j0=wg*4..j0+3 across
// the 4 gates => N=16 output rows (n = gate*4 + jc). Wave = M-tile (16 batches).
// K = 1024 = 16 x-ktiles + 16 h-ktiles of mfma_f32_16x16x32_bf16.
// Weights: 32 B-fragments (128 VGPR/lane), loaded once before the t-loop.
// h crosses WGs as bf16 in A-fragment layout via a ws ping-pong buffer using
// RELAXED+AGENT atomics (sc1: no buffer_inv / buffer_wbl2 anywhere).
__global__ __launch_bounds__(NTH, 1)
void lstm_mfma(const float* __restrict__ x,
               const float* __restrict__ Wf, const float* __restrict__ bfp,
               const float* __restrict__ Wi, const float* __restrict__ bip,
               const float* __restrict__ Wg, const float* __restrict__ bgp,
               const float* __restrict__ Wo, const float* __restrict__ bop,
               float* __restrict__ out,
               unsigned int* __restrict__ barcnt,
               char* __restrict__ hbase)
{
    const int tid = threadIdx.x;
    const int l   = tid & 63;
    const int mt  = tid >> 6;              // wave = M-tile (batches mt*16..+15)
    const int wg  = blockIdx.x;
    const int j0  = wg * 4;

    const int n    = l & 15;               // output row (gate*4 + jc) in C cols
    const int khi  = l >> 4;               // k-group for A/B fragments

    // ---- load the 32 B-fragments (weights, bf16) into VGPRs, once ----------
    const float* Wn = (n < 8) ? ((n < 4) ? Wf : Wi) : ((n < 12) ? Wg : Wo);
    const float* wrow = Wn + (size_t)(j0 + (n & 3)) * KTOT + khi * 8;
    short8 Bfr[32];
    #pragma unroll
    for (int kt = 0; kt < 32; ++kt) {
        const float4 lo = *(const float4*)(wrow + kt * 32);
        const float4 hi = *(const float4*)(wrow + kt * 32 + 4);
        Bfr[kt] = cvt8(lo, hi);
    }
    const float biasn = ((n < 8) ? ((n < 4) ? bfp : bip)
                                 : ((n < 12) ? bgp : bop))[j0 + (n & 3)];

    // c-state: 4 values per jc-lane (lanes with (l>>2)&3 == 0)
    float cst0 = 0.f, cst1 = 0.f, cst2 = 0.f, cst3 = 0.f;

    float* const hx_out = out + (size_t)SEQ * BATCH * DH;
    float* const cx_out = hx_out + (size_t)BATCH * DH;

    // producer-side h-fragment coordinates (constant over t)
    const int kth    = wg >> 3;                         // h k-tile 0..15
    const int e_h    = (wg & 1) * 4 + (l & 3);          // elem 0..7 (jc-lanes)
    const int lane_f_base = ((wg & 7) >> 1) << 4;       // hi<<4

    const float* xrow_base = x + (size_t)(mt * 16 + (l & 15)) * DIN + khi * 8;

    for (int t = 0; t < SEQ; ++t) {
        f32x4 acc = {0.f, 0.f, 0.f, 0.f};

        // ---------- phase X: x[t] contribution (barrier-independent) -------
        {
            const float* xr = xrow_base + (size_t)t * BATCH * DIN;
            #pragma unroll
            for (int kt = 0; kt < 16; ++kt) {
                const float4 lo = *(const float4*)(xr + kt * 32);
                const float4 hi = *(const float4*)(xr + kt * 32 + 4);
                const short8 a = cvt8(lo, hi);
                acc = __builtin_amdgcn_mfma_f32_16x16x32_bf16(a, Bfr[kt], acc, 0, 0, 0);
            }
        }

        if (t > 0) {
            // ------ epoch barrier: relaxed polls only (no cache ops) -------
            if (tid == 0) {
                const unsigned int target = (unsigned int)NWG * (unsigned int)t;
                while (__hip_atomic_load(barcnt, __ATOMIC_RELAXED,
                                         __HIP_MEMORY_SCOPE_AGENT) < target) {
                    __builtin_amdgcn_s_sleep(1);
                }
            }
            __syncthreads();

            // ---------- phase H: h[t-1] via sc1 loads (L2-bypass) ----------
            const unsigned long long* hp =
                (const unsigned long long*)(hbase + ((t & 1) ^ 1) * HBUF_BYTES)
                + ((size_t)(mt * 16) * 64 + l) * 2;
            unsigned long long hv[32];
            #pragma unroll
            for (int kt = 0; kt < 16; ++kt) {
                hv[2 * kt]     = __hip_atomic_load(hp + kt * 128,     __ATOMIC_RELAXED,
                                                   __HIP_MEMORY_SCOPE_AGENT);
                hv[2 * kt + 1] = __hip_atomic_load(hp + kt * 128 + 1, __ATOMIC_RELAXED,
                                                   __HIP_MEMORY_SCOPE_AGENT);
            }
            #pragma unroll
            for (int kt = 0; kt < 16; ++kt) {
                union { unsigned long long u[2]; short8 v; } U;
                U.u[0] = hv[2 * kt];
                U.u[1] = hv[2 * kt + 1];
                acc = __builtin_amdgcn_mfma_f32_16x16x32_bf16(U.v, Bfr[16 + kt], acc, 0, 0, 0);
            }
        }

        // ---------- epilogue: gates, state update, stores ------------------
        // C layout: col n = l&15, row b16 = (l>>4)*4 + q
        const float p0 = acc[0] + biasn;
        const float p1 = acc[1] + biasn;
        const float p2 = acc[2] + biasn;
        const float p3 = acc[3] + biasn;

        const float i0 = __shfl_xor(p0, 4), g0 = __shfl_xor(p0, 8), o0 = __shfl_xor(p0, 12);
        const float i1 = __shfl_xor(p1, 4), g1 = __shfl_xor(p1, 8), o1 = __shfl_xor(p1, 12);
        const float i2 = __shfl_xor(p2, 4), g2 = __shfl_xor(p2, 8), o2 = __shfl_xor(p2, 12);
        const float i3 = __shfl_xor(p3, 4), g3 = __shfl_xor(p3, 8), o3 = __shfl_xor(p3, 12);

        if (((l >> 2) & 3) == 0) {          // jc-lanes: l&15 in 0..3
            const int jc = l & 3;
            const int j  = j0 + jc;
            const int b0 = mt * 16 + (l >> 4) * 4;   // q adds 0..3
            char* const wb = hbase + (t & 1) * HBUF_BYTES;

            float hq[4];
            cst0 = fmaf(sig_(p0), cst0, sig_(i0) * tanhf(g0)); hq[0] = sig_(o0) * tanhf(cst0);
            cst1 = fmaf(sig_(p1), cst1, sig_(i1) * tanhf(g1)); hq[1] = sig_(o1) * tanhf(cst1);
            cst2 = fmaf(sig_(p2), cst2, sig_(i2) * tanhf(g2)); hq[2] = sig_(o2) * tanhf(cst2);
            cst3 = fmaf(sig_(p3), cst3, sig_(i3) * tanhf(g3)); hq[3] = sig_(o3) * tanhf(cst3);

            #pragma unroll
            for (int q = 0; q < 4; ++q) {
                const int b = b0 + q;
                out[((size_t)t * BATCH + b) * DH + j] = hq[q];
                // h-fragment bf16 store for next step (sc1, L2-bypass)
                unsigned short* hp_w = (unsigned short*)
                    (wb + (((size_t)(mt * 16 + kth) * 64
                            + (lane_f_base | (b & 15))) << 4) + e_h * 2);
                __hip_atomic_store(hp_w, f2bf(hq[q]), __ATOMIC_RELAXED,
                                   __HIP_MEMORY_SCOPE_AGENT);
            }
            if (t == SEQ - 1) {
                #pragma unroll
                for (int q = 0; q < 4; ++q) {
                    const int b = b0 + q;
                    hx_out[(size_t)b * DH + j] = hq[q];
                }
                cx_out[(size_t)b0 * DH + j]       = cst0;
                cx_out[(size_t)(b0 + 1) * DH + j] = cst1;
                cx_out[(size_t)(b0 + 2) * DH + j] = cst2;
                cx_out[(size_t)(b0 + 3) * DH + j] = cst3;
            }
        }

        if (t < SEQ - 1) {
            __syncthreads();   // drains vmcnt(0) per wave before any signal
            if (tid == 0) {
                __hip_atomic_fetch_add(barcnt, 1u, __ATOMIC_RELAXED,
                                       __HIP_MEMORY_SCOPE_AGENT);
            }
        }
    }
}

extern "C" void kernel_launch(void* const* d_in, const int* in_sizes, int n_in,
                              void* d_out, int out_size, void* d_ws, size_t ws_size,
                              hipStream_t stream)
{
    const float* x  = (const float*)d_in[0];
    const float* Wf = (const float*)d_in[1];
    const float* bf = (const float*)d_in[2];
    const float* Wi = (const float*)d_in[3];
    const float* bi = (const float*)d_in[4];
    const float* Wg = (const float*)d_in[5];
    const float* bg = (const float*)d_in[6];
    const float* Wo = (const float*)d_in[7];
    const float* bo = (const float*)d_in[8];
    float* out = (float*)d_out;

    unsigned int* barcnt = (unsigned int*)d_ws;
    char* hbase = (char*)d_ws + 256;       // 2 x 64 KB ping-pong h buffers

    // Counter must be 0 every call (ws poisoned once, never re-poisoned).
    // h buffers need no init: buf[t&1] is written at step t before its read.
    hipMemsetAsync(d_ws, 0, 256, stream);

    lstm_mfma<<<NWG, NTH, 0, stream>>>(x, Wf, bf, Wi, bi, Wg, bg, Wo, bo,
                                       out, barcnt, hbase);
}